// Round 1
// 347.563 us; speedup vs baseline: 1.1781x; 1.1781x over previous
//
#include <hip/hip_runtime.h>

// Problem constants
#define D1 270
#define KK 32
#define CC 60
#define BB 64
#define TT 4096

#define KPAD 64    // c padded 60 -> 64
#define NT 128     // t-chunk per block (was 64)

typedef __bf16 bf16x8 __attribute__((ext_vector_type(8)));
typedef float f32x4 __attribute__((ext_vector_type(4)));

__device__ inline unsigned short f2bf(float f) {
    // round-to-nearest-even float -> bf16 bits (inputs are finite)
    unsigned int x = __builtin_bit_cast(unsigned int, f);
    unsigned int r = x + 0x7fffu + ((x >> 16) & 1u);
    return (unsigned short)(r >> 16);
}

// ---------------- Kernel 1 (fused): trig tables in LDS + a[j,c] + softmax ----
// grid = 270 blocks (one per j), block = 1024 (16 waves).
// Per-block LDS tables ckx/skx[k][c] = cos/sin(2*pi*k*x_c), cly/sly[l][c] for y.
// cos(2pi(kx+ly)) = ck*cl - sk*sl ; sin = sk*cl + ck*sl.
__global__ __launch_bounds__(1024) void wcalc_kernel(const float* __restrict__ zre,
                                                     const float* __restrict__ zim,
                                                     const float* __restrict__ loc,
                                                     unsigned short* __restrict__ wbf) {
    __shared__ float ckx[KK][64];
    __shared__ float skx[KK][64];
    __shared__ float cly[KK][64];
    __shared__ float sly[KK][64];
    __shared__ float red[16][64];

    const int tid = threadIdx.x;
    const int j = blockIdx.x;
    const int w = tid >> 6;
    const int lane = tid & 63;

    // ---- phase 1: build 32x60 sincos tables for x and y (3840 jobs) ----
    #pragma unroll
    for (int base = 0; base < 3840; base += 1024) {
        int jj = base + tid;
        if (jj < 3840) {
            int fam = jj / 1920;          // 0 = k*x, 1 = l*y
            int r = jj - fam * 1920;
            int k = r / 60;
            int c = r - k * 60;
            float coord = loc[2 * c + fam];
            float ph = 6.28318530717958647692f * ((float)k * coord);
            float s, co;
            sincosf(ph, &s, &co);
            if (fam == 0) { ckx[k][c] = co; skx[k][c] = s; }
            else          { cly[k][c] = co; sly[k][c] = s; }
        }
    }
    __syncthreads();

    // ---- phase 2: wave w handles k in {2w, 2w+1}, l in 0..31 ----
    const float* zr = zre + j * (KK * KK);
    const float* zi = zim + j * (KK * KK);
    float acc = 0.0f;
    if (lane < CC) {
        #pragma unroll
        for (int kh = 0; kh < 2; ++kh) {
            const int k = 2 * w + kh;
            const float ck = ckx[k][lane];
            const float sk = skx[k][lane];
            const float* zrk = zr + k * KK;
            const float* zik = zi + k * KK;
            #pragma unroll 8
            for (int l = 0; l < KK; ++l) {
                float cl = cly[l][lane];
                float sl = sly[l][lane];
                float cv = ck * cl - sk * sl;
                float sv = sk * cl + ck * sl;
                acc += zrk[l] * cv + zik[l] * sv;
            }
        }
    }
    red[w][lane] = acc;
    __syncthreads();

    // ---- phase 3: reduce over waves, softmax over c, write bf16 row ----
    if (w == 0) {
        float a = 0.0f;
        #pragma unroll
        for (int r = 0; r < 16; ++r) a += red[r][lane];
        float av = (lane < CC) ? a : -3.4e38f;
        #pragma unroll
        for (int o = 32; o > 0; o >>= 1) av = fmaxf(av, __shfl_xor(av, o, 64));
        float e = (lane < CC) ? expf(a - av) : 0.0f;
        float s = e;
        #pragma unroll
        for (int o = 32; o > 0; o >>= 1) s += __shfl_xor(s, o, 64);
        float wv = e / s;
        wbf[j * KPAD + lane] = (lane < CC) ? f2bf(wv) : (unsigned short)0;
    }
    // zero-fill padded j rows 270, 271 (done by blocks 0 and 1)
    if (j < 2 && w == 15) {
        wbf[(D1 + j) * KPAD + lane] = (unsigned short)0;
    }
}

// ---------------- Kernel 2: out[b,j,t] = sum_c w[j,c] * X[b,c,t] ------------
// D[t][j] = Xlds[t][c] x W^T : A-frag from LDS [t][c-contig], B-frag straight
// from global w[j][c-contig], C-frag -> float4 store along t.
// NT=128: grid = (T/128, B) = 2048 blocks, block = 256 (4 waves).
// Wave w owns m-tiles {2w, 2w+1} (t rows w*32 .. w*32+31).
// Stores are PLAIN (not nontemporal): the MFMA D-layout only gives 64B of
// contiguity per j-row per instruction; nt streamed half-dirty lines out of
// L2 before the sibling 64B half arrived. Plain stores let L2 merge them
// into full-line HBM writes.
__global__ __launch_bounds__(256, 4) void gemm_kernel(const float* __restrict__ X,
                                                      const unsigned short* __restrict__ Wb,
                                                      float* __restrict__ out) {
    __shared__ __align__(16) unsigned short xs[NT][72];  // [t][c] bf16, stride 144B

    const int tid = threadIdx.x;
    const int chunk = blockIdx.x;
    const int b = blockIdx.y;
    const long t0 = (long)chunk * NT;

    // ---- stage X[b, 0..59, t0..t0+127] -> bf16 LDS, zero-pad c=60..63 ----
    {
        const int lane63 = tid & 63;
        const int cg = tid >> 6;      // 0..3
        #pragma unroll
        for (int th = 0; th < 2; ++th) {
            const int n = th * 64 + lane63;   // t within chunk, 0..127
            const float* Xb = X + (long)b * (CC * (long)TT) + t0 + n;
            #pragma unroll
            for (int r = 0; r < 4; ++r) {
                int c0 = cg * 4 + r * 16;  // multiple of 4, covers 0..63
                unsigned int u01, u23;
                {
                    float v0 = (c0 + 0 < CC) ? __builtin_nontemporal_load(&Xb[(long)(c0 + 0) * TT]) : 0.0f;
                    float v1 = (c0 + 1 < CC) ? __builtin_nontemporal_load(&Xb[(long)(c0 + 1) * TT]) : 0.0f;
                    float v2 = (c0 + 2 < CC) ? __builtin_nontemporal_load(&Xb[(long)(c0 + 2) * TT]) : 0.0f;
                    float v3 = (c0 + 3 < CC) ? __builtin_nontemporal_load(&Xb[(long)(c0 + 3) * TT]) : 0.0f;
                    u01 = (unsigned int)f2bf(v0) | ((unsigned int)f2bf(v1) << 16);
                    u23 = (unsigned int)f2bf(v2) | ((unsigned int)f2bf(v3) << 16);
                }
                uint2 val; val.x = u01; val.y = u23;
                *reinterpret_cast<uint2*>(&xs[n][c0]) = val;   // 8B-aligned
            }
        }
    }
    __syncthreads();

    // ---- MFMA: D[t][j], 2 m-tiles per wave ----
    const int w = tid >> 6;
    const int lane = tid & 63;
    const int q = lane >> 4;
    const int l15 = lane & 15;

    bf16x8 a[2][2];   // [m-tile][k-group]
    #pragma unroll
    for (int mt = 0; mt < 2; ++mt) {
        const int trow = (w * 2 + mt) * 16 + l15;  // A m-row in LDS
        a[mt][0] = *reinterpret_cast<const bf16x8*>(&xs[trow][q * 8]);        // k = 0..31
        a[mt][1] = *reinterpret_cast<const bf16x8*>(&xs[trow][32 + q * 8]);   // k = 32..63
    }

    float* outp = out + (long)b * ((long)D1 * TT) + t0 + w * 32 + q * 4;

    #pragma unroll 4
    for (int jt = 0; jt < 17; ++jt) {
        const int j = jt * 16 + l15;
        const unsigned short* wrow = Wb + j * KPAD;   // rows 270/271 are zero-filled
        bf16x8 b0 = *reinterpret_cast<const bf16x8*>(&wrow[q * 8]);        // B[k=q*8+i][n=l15]
        bf16x8 b1 = *reinterpret_cast<const bf16x8*>(&wrow[32 + q * 8]);
        #pragma unroll
        for (int mt = 0; mt < 2; ++mt) {
            // MFMA must run with full exec (whole-wave op); only the store is
            // predicated. Out-of-range j reads the zero-filled pad rows.
            f32x4 acc = {0.0f, 0.0f, 0.0f, 0.0f};
            acc = __builtin_amdgcn_mfma_f32_16x16x32_bf16(a[mt][0], b0, acc, 0, 0, 0);
            acc = __builtin_amdgcn_mfma_f32_16x16x32_bf16(a[mt][1], b1, acc, 0, 0, 0);
            if (j < D1) {
                *reinterpret_cast<f32x4*>(outp + (long)j * TT + mt * 16) = acc;
            }
        }
    }
}

extern "C" void kernel_launch(void* const* d_in, const int* in_sizes, int n_in,
                              void* d_out, int out_size, void* d_ws, size_t ws_size,
                              hipStream_t stream) {
    const float* X   = (const float*)d_in[0];
    const float* zre = (const float*)d_in[1];
    const float* zim = (const float*)d_in[2];
    const float* loc = (const float*)d_in[3];
    float* out = (float*)d_out;

    unsigned short* wbf = (unsigned short*)d_ws;  // [272][64] bf16 in workspace

    wcalc_kernel<<<D1, 1024, 0, stream>>>(zre, zim, loc, wbf);
    gemm_kernel<<<dim3(TT / NT, BB), 256, 0, stream>>>(X, wbf, out);
}